// Round 2
// baseline (357.233 us; speedup 1.0000x reference)
//
#include <hip/hip_runtime.h>

// Scaled dot-product attention, B=8, S=2048, D=512, fp32 in/out.
// d_out = context [B,S,D] fp32 ++ attention_weights [B,S,S] fp32.
//
// R5: scores GEMM ported to the 256x256 8-phase counted-vmcnt template
//     (T2 swizzle + T3/T4 phases + T5 setprio + T1 XCD pinning).
//     Everything else identical to R4.
//   1. convert_qk:  Q*scale,K fp32 -> bf16 Qbf,Kbf                  (ws)
//   2. transpose_v: V fp32 [b][s][d] -> Vt bf16 [b][d][s]           (ws)
//   3. scores8:     Pbf = bf16(exp(Qbf Kbf^T))  (NT 256x256x64, 8-phase)
//   4. normalize:   row-sum of Pbf -> W fp32 (d_out) + inv_s[B*S]   (ws)
//   5. context:     C = (Pbf Vt^T) * inv_s[row]   (NT, m97 128x128 loop)

constexpr int BATCH = 8;
constexpr int SEQ = 2048;
constexpr int DIM = 512;
constexpr size_t QK_ELEMS = (size_t)BATCH * SEQ * DIM;   // 8,388,608
constexpr size_t SS_ELEMS = (size_t)BATCH * SEQ * SEQ;   // 33,554,432

typedef __attribute__((ext_vector_type(8))) short bh8;            // MFMA A/B frag
typedef __attribute__((ext_vector_type(8))) unsigned short u16x8; // 16B copy unit
typedef __attribute__((ext_vector_type(4))) float f4acc;          // MFMA C/D

__device__ __forceinline__ short f2bf(float f) {
  union { float f; unsigned u; } v;
  v.f = f;
  unsigned r = (v.u + 0x7FFFu + ((v.u >> 16) & 1u)) >> 16;
  return (short)r;
}

__device__ __forceinline__ float bf2f(unsigned short h) {
  union { unsigned u; float f; } v;
  v.u = (unsigned)h << 16;
  return v.f;
}

// async 16B global->LDS DMA; LDS dest must be wave-uniform base + lane*16
__device__ __forceinline__ void glds16(const unsigned short* g,
                                       unsigned short* l) {
  __builtin_amdgcn_global_load_lds(
      (const __attribute__((address_space(1))) unsigned int*)g,
      (__attribute__((address_space(3))) unsigned int*)l, 16, 0, 0);
}

// ---------------------------------------------------------------------------
// Q -> Qbf*scale, K -> Kbf. 8 floats/thread, 16B bf16 stores.
__global__ __launch_bounds__(256) void convert_qk_kernel(
    const float* __restrict__ Q, const float* __restrict__ K,
    unsigned short* __restrict__ Qbf, unsigned short* __restrict__ Kbf) {
  const size_t i = ((size_t)blockIdx.x * 256 + threadIdx.x) * 8;
  const float sc = blockIdx.y ? 1.0f : 0.044194173824159216f;  // 1/sqrt(512)
  const float* src = blockIdx.y ? K : Q;
  unsigned short* dst = blockIdx.y ? Kbf : Qbf;
  float4 a = *(const float4*)(src + i);
  float4 b = *(const float4*)(src + i + 4);
  bh8 o;
  o[0] = f2bf(a.x * sc); o[1] = f2bf(a.y * sc);
  o[2] = f2bf(a.z * sc); o[3] = f2bf(a.w * sc);
  o[4] = f2bf(b.x * sc); o[5] = f2bf(b.y * sc);
  o[6] = f2bf(b.z * sc); o[7] = f2bf(b.w * sc);
  *(bh8*)(dst + i) = o;
}

// ---------------------------------------------------------------------------
// V [B,S,D] fp32 -> Vt [B,D,S] bf16 (32x32 LDS tile transpose)
__global__ __launch_bounds__(256) void transpose_v_kernel(
    const float* __restrict__ V, unsigned short* __restrict__ Vt) {
  __shared__ float tile[32][33];
  const int s0 = blockIdx.x * 32, d0 = blockIdx.y * 32, b = blockIdx.z;
  const float* Vb = V + (size_t)b * SEQ * DIM;
  unsigned short* Vtb = Vt + (size_t)b * DIM * SEQ;
  const int tx = threadIdx.x & 31, ty = threadIdx.x >> 5;  // 32 x 8
  for (int r = 0; r < 32; r += 8)
    tile[ty + r][tx] = Vb[(size_t)(s0 + ty + r) * DIM + (d0 + tx)];
  __syncthreads();
  for (int r = 0; r < 32; r += 8)
    Vtb[(size_t)(d0 + ty + r) * SEQ + (s0 + tx)] =
        (unsigned short)f2bf(tile[tx][ty + r]);
}

// ---------------------------------------------------------------------------
// scores8: Pbf = bf16(exp(Qbf Kbf^T)), 256x256 tile, BK=64, 8 waves (2Mx4N),
// 8-phase counted-vmcnt schedule (guide §5 template, m201-derived ledger).
//
// LDS (128 KiB, ushort offsets): slot(2, one K-tile each) x
//   { A-s0 [256][32] @0, A-s1 @8192, B-s0 @16384, B-s1 @24576 }.
// A K-tile's 4 staged "quarters" = (matrix, k-slice): retire-clean vs the
// quadrant order (s0,m0)(s0,m4)(s1,m0)(s1,m4).
// T2 swizzle (64B rows): LDS[row][c] holds global chunk c^(row&3); applied
// as pre-swizzled GLOBAL source (glds writes linearly) + swizzled ds_read.
//
// Ledger (quarters, 2 glds each): prologue h0..h3 (tile0), vm(4), h4..h6,
// vm(6), barrier. Iter i (tiles 2i,2i+1): p0 stages h(7+8i)=tile(2i+1).Bs1;
// p1-4: tile(2i+2) quarters; p5-7: tile(2i+3) first 3. Gates vm(6) after
// p3 and p7 land exactly the next-consumed tile. Tail iter: vm(0) at p3.
__global__ __launch_bounds__(512, 2) void scores8_kernel(
    const unsigned short* __restrict__ Qbf,
    const unsigned short* __restrict__ Kbf,
    unsigned short* __restrict__ Pbf) {
  __shared__ __align__(16) unsigned short sm[65536];  // 128 KiB
  // T1: pin batch <-> XCD (512 blocks, 512 % 8 == 0 -> simple bijection)
  const int id = blockIdx.x;
  const int swz = (id & 7) * 64 + (id >> 3);
  const int b = swz >> 6, local = swz & 63, bm = local & 7, bn = local >> 3;
  const int tid = threadIdx.x, lane = tid & 63, wave = tid >> 6;
  const int wm = (wave >> 2) * 128, wn = (wave & 3) * 64;
  const int fr = lane & 15, c16 = lane >> 4;  // frag row-in-16 / 16B chunk
  // staging: thread covers row r0 (+128 for 2nd issue) of a [256][32bf16]
  // quarter; source col chunk pre-swizzled so LDS[r][c] = global[r][c^(r&3)]
  const int r0 = tid >> 2;                        // 0..127
  const int cbs = (((tid & 3) ^ (r0 & 3)) << 3);  // swizzled src col (bf16)
  const unsigned short* Ag =
      Qbf + ((size_t)b * SEQ + bm * 256 + r0) * DIM + cbs;
  const unsigned short* Bg =
      Kbf + ((size_t)b * SEQ + bn * 256 + r0) * DIM + cbs;
  unsigned short* smt = sm + tid * 8;  // linear lane slot in each quarter

  auto stage = [&](int h) {  // h = global quarter index, uniform
    const int T = h >> 2, part = h & 3;           // part: 0 As0 1 Bs0 2 As1 3 Bs1
    const unsigned short* src =
        ((part & 1) ? Bg : Ag) + T * 64 + (part >> 1) * 32;
    unsigned short* l = smt + (T & 1) * 32768 + (part & 1) * 16384 +
                        ((part >> 1) ^ ((part & 1) ? 0 : 0)) * 8192;
    l = smt + (T & 1) * 32768 + (part & 1) * 16384 + (part >> 1) * 8192;
    glds16(src, l);
    glds16(src + (size_t)128 * DIM, l + 4096);
  };

  f4acc acc[8][4] = {};

#define PHASE(SLOT, SLICE, MIB, STAGE_STMT, GATE_STMT)                        \
  {                                                                           \
    bh8 a[4], bfr[4];                                                         \
    const unsigned short* As = sm + (SLOT)*32768 + (SLICE)*8192;              \
    const unsigned short* Bs = As + 16384;                                    \
    _Pragma("unroll") for (int i = 0; i < 4; ++i) {                           \
      const int ra = wm + ((MIB) + i) * 16 + fr;                              \
      a[i] = *(const bh8*)(As + ra * 32 + ((c16 ^ (ra & 3)) << 3));           \
      const int rb = wn + i * 16 + fr;                                        \
      bfr[i] = *(const bh8*)(Bs + rb * 32 + ((c16 ^ (rb & 3)) << 3));         \
    }                                                                         \
    STAGE_STMT;                                                               \
    asm volatile("s_barrier" ::: "memory");                                   \
    asm volatile("s_waitcnt lgkmcnt(0)" ::: "memory");                        \
    __builtin_amdgcn_s_setprio(1);                                            \
    _Pragma("unroll") for (int mi = 0; mi < 4; ++mi)                          \
      _Pragma("unroll") for (int ni = 0; ni < 4; ++ni)                        \
        acc[(MIB) + mi][ni] = __builtin_amdgcn_mfma_f32_16x16x32_bf16(        \
            a[mi], bfr[ni], acc[(MIB) + mi][ni], 0, 0, 0);                    \
    __builtin_amdgcn_s_setprio(0);                                            \
    GATE_STMT;                                                                \
    asm volatile("s_barrier" ::: "memory");                                   \
  }

  // prologue: tile0 fully + tile1 first 3 quarters, counted gates
  stage(0); stage(1); stage(2); stage(3);
  asm volatile("s_waitcnt vmcnt(4)" ::: "memory");
  stage(4); stage(5); stage(6);
  asm volatile("s_waitcnt vmcnt(6)" ::: "memory");
  asm volatile("s_barrier" ::: "memory");

  int hs = 7;  // next quarter to stage (uniform); 32 total (8 K-tiles)
#pragma unroll 1
  for (int it = 0; it < 4; ++it) {
    PHASE(0, 0, 0, if (hs < 32) stage(hs++), )
    PHASE(0, 0, 4, if (hs < 32) stage(hs++), )
    PHASE(0, 1, 0, if (hs < 32) stage(hs++), )
    PHASE(0, 1, 4, if (hs < 32) stage(hs++),
          if (it == 3) { asm volatile("s_waitcnt vmcnt(0)" ::: "memory"); }
          else { asm volatile("s_waitcnt vmcnt(6)" ::: "memory"); })
    PHASE(1, 0, 0, if (hs < 32) stage(hs++), )
    PHASE(1, 0, 4, if (hs < 32) stage(hs++), )
    PHASE(1, 1, 0, if (hs < 32) stage(hs++), )
    PHASE(1, 1, 4, if (hs < 32) stage(hs++),
          if (it < 3) { asm volatile("s_waitcnt vmcnt(6)" ::: "memory"); })
  }
#undef PHASE

  __syncthreads();
  // epilogue: acc -> exp -> bf16, swizzled [256][32 chunk] LDS, stream out.
  // C/D layout (16x16x32): col = lane&15, row = (lane>>4)*4 + r.
  const int rl = (lane >> 4) << 2, cl = lane & 15;
#pragma unroll
  for (int mi = 0; mi < 8; ++mi)
#pragma unroll
    for (int ni = 0; ni < 4; ++ni)
#pragma unroll
      for (int r = 0; r < 4; ++r) {
        const int row = wm + mi * 16 + rl + r;
        const int col = wn + ni * 16 + cl;
        sm[row * 256 + (((col >> 3) ^ (row & 7)) << 3) + (col & 7)] =
            (unsigned short)f2bf(__expf(acc[mi][ni][r]));
      }
  __syncthreads();
  unsigned short* Pg =
      Pbf + (size_t)b * SEQ * SEQ + (size_t)(bm * 256) * SEQ + bn * 256;
#pragma unroll
  for (int i = 0; i < 16; ++i) {
    const int idx = i * 512 + tid;
    const int row = idx >> 5, ch = idx & 31;
    *(u16x8*)(Pg + (size_t)row * SEQ + ch * 8) =
        *(const u16x8*)(sm + row * 256 + ((ch ^ (row & 7)) << 3));
  }
}

// ---------------------------------------------------------------------------
// BK=64 NT main loop (m97 structure) — still used by context_kernel.
template <int KDIM>
__device__ __forceinline__ void gemm_loop_nt(
    const unsigned short* __restrict__ A, const unsigned short* __restrict__ B,
    unsigned short* sm, f4acc acc[4][4]) {
  const int tid = threadIdx.x, lane = tid & 63, wave = tid >> 6;
  const int wm = (wave & 1) * 64, wn = (wave >> 1) * 64;
  const int srow = wave * 32 + (lane >> 2), scol = (lane & 3) * 8;
  const unsigned short* Ag = A + (size_t)srow * KDIM + scol;
  const unsigned short* Bg = B + (size_t)srow * KDIM + scol;
  unsigned short* As0 = sm;
  unsigned short* As1 = sm + 4096;
  unsigned short* Bs0 = sm + 8192;
  unsigned short* Bs1 = sm + 12288;
  unsigned short* Al0 = As0 + srow * 32 + scol;
  unsigned short* Al1 = As1 + srow * 32 + scol;
  unsigned short* Bl0 = Bs0 + srow * 32 + scol;
  unsigned short* Bl1 = Bs1 + srow * 32 + scol;
  const int fr = lane & 15, fk = (lane >> 4) * 8;
#pragma unroll 2
  for (int k0 = 0; k0 < KDIM; k0 += 64) {
    glds16(Ag + k0,                        Al0);
    glds16(Ag + k0 + (size_t)16 * KDIM,    Al0 + 512);
    glds16(Ag + k0 + 32,                   Al1);
    glds16(Ag + k0 + 32 + (size_t)16 * KDIM, Al1 + 512);
    glds16(Bg + k0,                        Bl0);
    glds16(Bg + k0 + (size_t)16 * KDIM,    Bl0 + 512);
    glds16(Bg + k0 + 32,                   Bl1);
    glds16(Bg + k0 + 32 + (size_t)16 * KDIM, Bl1 + 512);
    __syncthreads();
    bh8 a0[4], a1[4], b0[4], b1[4];
    for (int i = 0; i < 4; ++i) {
      a0[i] = *(const bh8*)(As0 + (wm + i * 16 + fr) * 32 + fk);
      a1[i] = *(const bh8*)(As1 + (wm + i * 16 + fr) * 32 + fk);
      b0[i] = *(const bh8*)(Bs0 + (wn + i * 16 + fr) * 32 + fk);
      b1[i] = *(const bh8*)(Bs1 + (wn + i * 16 + fr) * 32 + fk);
    }
    for (int mi = 0; mi < 4; ++mi)
      for (int ni = 0; ni < 4; ++ni)
        acc[mi][ni] = __builtin_amdgcn_mfma_f32_16x16x32_bf16(
            a0[mi], b0[ni], acc[mi][ni], 0, 0, 0);
    for (int mi = 0; mi < 4; ++mi)
      for (int ni = 0; ni < 4; ++ni)
        acc[mi][ni] = __builtin_amdgcn_mfma_f32_16x16x32_bf16(
            a1[mi], b1[ni], acc[mi][ni], 0, 0, 0);
    __syncthreads();
  }
}

// ---------------------------------------------------------------------------
// Row normalize: reads Pbf (bf16 exp values), computes row sum, writes
// W = P * (1/s) fp32 (d_out) and inv_s[row] (ws) for the context epilogue.
__global__ __launch_bounds__(256) void normalize_kernel(
    const unsigned short* __restrict__ Pbf, float* __restrict__ W,
    float* __restrict__ inv_s) {
  const size_t row = blockIdx.x;
  const int tid = threadIdx.x, lane = tid & 63, wave = tid >> 6;
  u16x8 v = *(const u16x8*)(Pbf + row * SEQ + tid * 8);
  float x[8];
  float s = 0.f;
  for (int j = 0; j < 8; ++j) { x[j] = bf2f(v[j]); s += x[j]; }
  for (int off = 32; off > 0; off >>= 1) s += __shfl_xor(s, off);
  __shared__ float reds[4];
  if (lane == 0) reds[wave] = s;
  __syncthreads();
  s = reds[0] + reds[1] + reds[2] + reds[3];
  const float inv = 1.0f / s;
  if (tid == 0) inv_s[row] = inv;
  float4 o0 = {x[0] * inv, x[1] * inv, x[2] * inv, x[3] * inv};
  float4 o1 = {x[4] * inv, x[5] * inv, x[6] * inv, x[7] * inv};
  float* Wr = W + row * SEQ + tid * 8;
  *(float4*)Wr = o0;
  *(float4*)(Wr + 4) = o1;
}

// ---------------------------------------------------------------------------
// Context: C = (Pbf * Vt^T) * inv_s[row] (fp32 out, direct strided stores).
__global__ __launch_bounds__(256) void context_kernel(
    const unsigned short* __restrict__ Pbf,
    const unsigned short* __restrict__ Vt,
    const float* __restrict__ inv_s, float* __restrict__ C) {
  __shared__ unsigned short sm[16384];
  const int bm = blockIdx.x, bn = blockIdx.y, b = blockIdx.z;
  const int tid = threadIdx.x, lane = tid & 63, wave = tid >> 6;
  const int wm = (wave & 1) * 64, wn = (wave >> 1) * 64;
  f4acc acc[4][4] = {};
  gemm_loop_nt<SEQ>(Pbf + ((size_t)b * SEQ + bm * 128) * SEQ,
                    Vt + ((size_t)b * DIM + bn * 128) * SEQ, sm, acc);
  float* Cb = C + (size_t)b * SEQ * DIM + (size_t)(bm * 128) * DIM + bn * 128;
  const float* invb = inv_s + (size_t)b * SEQ + bm * 128;
  const int cc = lane & 15, rr = (lane >> 4) * 4;
  for (int mi = 0; mi < 4; ++mi) {
    float iv[4];
    for (int r = 0; r < 4; ++r) iv[r] = invb[wm + mi * 16 + rr + r];
    for (int ni = 0; ni < 4; ++ni)
      for (int r = 0; r < 4; ++r)
        Cb[(size_t)(wm + mi * 16 + rr + r) * DIM + (wn + ni * 16 + cc)] =
            acc[mi][ni][r] * iv[r];
  }
}

// ---------------------------------------------------------------------------
extern "C" void kernel_launch(void* const* d_in, const int* in_sizes, int n_in,
                              void* d_out, int out_size, void* d_ws,
                              size_t ws_size, hipStream_t stream) {
  const float* Q = (const float*)d_in[0];
  const float* K = (const float*)d_in[1];
  const float* V = (const float*)d_in[2];
  float* C = (float*)d_out;                      // context [B,S,D]
  float* W = (float*)d_out + QK_ELEMS;           // weights [B,S,S]
  unsigned short* Qbf = (unsigned short*)d_ws;   // bf16 [B,S,D]   16.8 MB
  unsigned short* Kbf = Qbf + QK_ELEMS;          // bf16 [B,S,D]   16.8 MB
  unsigned short* Vt  = Kbf + QK_ELEMS;          // bf16 [B,D,S]   16.8 MB
  unsigned short* Pbf = Vt + QK_ELEMS;           // bf16 [B,S,S]   67.1 MB
  float* inv_s = (float*)(Pbf + SS_ELEMS);       // fp32 [B*S]     64 KB

  convert_qk_kernel<<<dim3((unsigned)(QK_ELEMS / 8 / 256), 2), 256, 0, stream>>>(
      Q, K, Qbf, Kbf);
  transpose_v_kernel<<<dim3(SEQ / 32, DIM / 32, BATCH), 256, 0, stream>>>(V, Vt);
  scores8_kernel<<<dim3(512), 512, 0, stream>>>(Qbf, Kbf, Pbf);
  normalize_kernel<<<dim3(BATCH * SEQ), 256, 0, stream>>>(Pbf, W, inv_s);
  context_kernel<<<dim3(SEQ / 128, DIM / 128, BATCH), 256, 0, stream>>>(Pbf, Vt, inv_s, C);
}